// Round 1
// baseline (546.727 us; speedup 1.0000x reference)
//
#include <hip/hip_runtime.h>
#include <hip/hip_bf16.h>
#include <stdint.h>

#define QL   2048
#define KLn  2048
#define DIM  512
#define NH   8
#define DH   64
#define NB   2
#define MROWS (NB*QL)   // 4096
#define FFD  2048

typedef unsigned short u16;
typedef __attribute__((ext_vector_type(8))) short short8;
typedef __attribute__((ext_vector_type(4))) float f32x4;

__device__ __forceinline__ float b2f(u16 u){
  union { unsigned int i; float f; } v; v.i = ((unsigned int)u) << 16; return v.f;
}
__device__ __forceinline__ u16 f2b(float f){
  union { float f; unsigned int i; } v; v.f = f;
  unsigned int r = v.i + 0x7FFFu + ((v.i >> 16) & 1u);
  return (u16)(r >> 16);
}

typedef __attribute__((address_space(3))) void as3void;
typedef __attribute__((address_space(1))) void as1void;
__device__ __forceinline__ void gload_lds16(const void* g, void* l){
  __builtin_amdgcn_global_load_lds((as1void*)g, (as3void*)l, 16, 0, 0);
}

// ---------------------------------------------------------------- GEMM
// C[M,N] = A[M,K](bf16) * Bt[N,K]^T(bf16) + bias, M multiple of 128, N of 128, K of 32
#define BM 128
#define BN 128
#define BK 32
enum { EPI_BIAS=0, EPI_SCALEQ=1, EPI_RELU=2, EPI_RES=3 };

template<int EPI>
__global__ __launch_bounds__(256, 2)
void gemm_bt(const u16* __restrict__ A, const u16* __restrict__ Bt,
             const float* __restrict__ bias,
             u16* __restrict__ Obf, float* __restrict__ Ores,
             int K, int N)
{
  __shared__ __align__(16) u16 As[BM*BK];
  __shared__ __align__(16) u16 Bs[BN*BK];
  const int t  = threadIdx.x;
  const int l  = t & 63;
  const int lq = l & 15, lg = l >> 4;
  const int w  = t >> 6;
  const int wm = (w >> 1) * 64;
  const int wn = (w & 1) * 64;
  const int m0 = blockIdx.y * BM;
  const int n0 = blockIdx.x * BN;

  const int srow  = t >> 2;        // 0..63
  const int skseg = (t & 3) * 8;   // 0,8,16,24

  const u16* Ag = A  + (size_t)(m0 + srow) * K + skseg;
  const u16* Bg = Bt + (size_t)(n0 + srow) * K + skseg;
  u16* As0 = &As[srow*BK + skseg];
  u16* As1 = &As[(srow+64)*BK + skseg];
  u16* Bs0 = &Bs[srow*BK + skseg];
  u16* Bs1 = &Bs[(srow+64)*BK + skseg];
  const size_t rowhop = (size_t)64 * K;

  f32x4 acc[4][4];
  #pragma unroll
  for (int i=0;i<4;i++)
    #pragma unroll
    for (int j=0;j<4;j++) acc[i][j] = (f32x4){0.f,0.f,0.f,0.f};

  for (int k0 = 0; k0 < K; k0 += BK){
    gload_lds16(Ag + k0,          As0);
    gload_lds16(Ag + k0 + rowhop, As1);
    gload_lds16(Bg + k0,          Bs0);
    gload_lds16(Bg + k0 + rowhop, Bs1);
    __syncthreads();
    short8 af[4], bf[4];
    #pragma unroll
    for (int i=0;i<4;i++) af[i] = *(const short8*)&As[(wm + i*16 + lq)*BK + lg*8];
    #pragma unroll
    for (int j=0;j<4;j++) bf[j] = *(const short8*)&Bs[(wn + j*16 + lq)*BK + lg*8];
    #pragma unroll
    for (int i=0;i<4;i++)
      #pragma unroll
      for (int j=0;j<4;j++)
        acc[i][j] = __builtin_amdgcn_mfma_f32_16x16x32_bf16(af[i], bf[j], acc[i][j], 0,0,0);
    __syncthreads();
  }

  #pragma unroll
  for (int i=0;i<4;i++){
    #pragma unroll
    for (int j=0;j<4;j++){
      #pragma unroll
      for (int r=0;r<4;r++){
        const int row = m0 + wm + i*16 + lg*4 + r;
        const int col = n0 + wn + j*16 + lq;
        float v = acc[i][j][r] + bias[col];
        if (EPI == EPI_SCALEQ) v *= 0.125f;
        if (EPI == EPI_RELU)   v = fmaxf(v, 0.f);
        if (EPI == EPI_RES)    Ores[(size_t)row*N + col] += v;
        else                   Obf[(size_t)row*N + col] = f2b(v);
      }
    }
  }
}

// ---------------------------------------------------------------- attention
// one wave per 16-row q tile; online softmax over kv tiles of 32
template<bool CAUSAL>
__global__ __launch_bounds__(64)
void attn_kernel(const u16* __restrict__ Q, const u16* __restrict__ Kb,
                 const u16* __restrict__ Vt, const int* __restrict__ mkpm,
                 u16* __restrict__ O)
{
  const int l  = threadIdx.x;
  const int lq = l & 15, lg = l >> 4;
  const int q0 = blockIdx.x * 16;
  const int h  = blockIdx.y;
  const int b  = blockIdx.z;

  short8 aq[2];
  #pragma unroll
  for (int kc = 0; kc < 2; ++kc)
    aq[kc] = *(const short8*)(Q + (size_t)(b*QL + q0 + lq)*DIM + h*DH + kc*32 + lg*8);

  f32x4 ctx[4];
  #pragma unroll
  for (int d = 0; d < 4; ++d) ctx[d] = (f32x4){0.f,0.f,0.f,0.f};
  float mrow[4], lrow[4];
  #pragma unroll
  for (int r = 0; r < 4; ++r){ mrow[r] = -INFINITY; lrow[r] = 0.f; }

  __shared__ __align__(16) u16 Plds[16*32];

  const int ntiles = CAUSAL ? ((q0 + 16 + 31) >> 5) : (KLn >> 5);
  for (int t = 0; t < ntiles; ++t){
    const int kvs = t * 32;
    f32x4 s[2];
    s[0] = (f32x4){0.f,0.f,0.f,0.f};
    s[1] = (f32x4){0.f,0.f,0.f,0.f};
    #pragma unroll
    for (int sub = 0; sub < 2; ++sub){
      const int kv = kvs + sub*16 + lq;
      #pragma unroll
      for (int kc = 0; kc < 2; ++kc){
        short8 bk = *(const short8*)(Kb + (size_t)(b*KLn + kv)*DIM + h*DH + kc*32 + lg*8);
        s[sub] = __builtin_amdgcn_mfma_f32_16x16x32_bf16(aq[kc], bk, s[sub], 0,0,0);
      }
    }
    if (CAUSAL){
      #pragma unroll
      for (int sub = 0; sub < 2; ++sub){
        const int kv = kvs + sub*16 + lq;
        #pragma unroll
        for (int r = 0; r < 4; ++r)
          if (kv > q0 + lg*4 + r) s[sub][r] = -INFINITY;
      }
    } else {
      #pragma unroll
      for (int sub = 0; sub < 2; ++sub){
        const int kv = kvs + sub*16 + lq;
        if (mkpm[b*KLn + kv] == 0){
          #pragma unroll
          for (int r = 0; r < 4; ++r) s[sub][r] = -INFINITY;
        }
      }
    }
    float p[2][4], corr[4];
    #pragma unroll
    for (int r = 0; r < 4; ++r){
      float tm = fmaxf(s[0][r], s[1][r]);
      #pragma unroll
      for (int off = 1; off < 16; off <<= 1)
        tm = fmaxf(tm, __shfl_xor(tm, off));
      const float mnew = fmaxf(mrow[r], tm);
      corr[r] = expf(mrow[r] - mnew);
      const float p0 = expf(s[0][r] - mnew);
      const float p1 = expf(s[1][r] - mnew);
      p[0][r] = p0; p[1][r] = p1;
      float rs = p0 + p1;
      #pragma unroll
      for (int off = 1; off < 16; off <<= 1)
        rs += __shfl_xor(rs, off);
      lrow[r] = lrow[r]*corr[r] + rs;
      mrow[r] = mnew;
    }
    #pragma unroll
    for (int d = 0; d < 4; ++d)
      #pragma unroll
      for (int r = 0; r < 4; ++r)
        ctx[d][r] *= corr[r];
    #pragma unroll
    for (int sub = 0; sub < 2; ++sub)
      #pragma unroll
      for (int r = 0; r < 4; ++r)
        Plds[(lg*4 + r)*32 + sub*16 + lq] = f2b(p[sub][r]);
    __syncthreads();
    short8 pf = *(const short8*)&Plds[lq*32 + lg*8];
    #pragma unroll
    for (int d = 0; d < 4; ++d){
      short8 bv = *(const short8*)(Vt + (size_t)(b*DIM + h*DH + d*16 + lq)*KLn + kvs + lg*8);
      ctx[d] = __builtin_amdgcn_mfma_f32_16x16x32_bf16(pf, bv, ctx[d], 0,0,0);
    }
    __syncthreads();
  }
  #pragma unroll
  for (int d = 0; d < 4; ++d)
    #pragma unroll
    for (int r = 0; r < 4; ++r)
      O[(size_t)(b*QL + q0 + lg*4 + r)*DIM + h*DH + d*16 + lq] = f2b(ctx[d][r] / lrow[r]);
}

// ---------------------------------------------------------------- layernorm
// MODE 0: x = in0+in1 -> xres(f32); out = LN(x)*g+b then * tkpm[row] (bf16)
// MODE 1: x = in0;                  out = LN(x)*g+b                  (bf16)
template<int MODE>
__global__ __launch_bounds__(128)
void ln_kernel(const float* __restrict__ in0, const float* __restrict__ in1,
               const float* __restrict__ tkpm,
               const float* __restrict__ g, const float* __restrict__ bvec,
               float* __restrict__ xres, u16* __restrict__ outb)
{
  const int row = blockIdx.x;
  const int t = threadIdx.x;
  float v[4];
  #pragma unroll
  for (int i = 0; i < 4; ++i){
    const int c = t + i*128;
    float x = in0[(size_t)row*DIM + c];
    if (MODE == 0){
      x += in1[(size_t)row*DIM + c];
      xres[(size_t)row*DIM + c] = x;
    }
    v[i] = x;
  }
  float s = v[0]+v[1]+v[2]+v[3];
  #pragma unroll
  for (int off = 1; off < 64; off <<= 1) s += __shfl_xor(s, off);
  __shared__ float red[4];
  if ((t & 63) == 0) red[t >> 6] = s;
  __syncthreads();
  const float mean = (red[0] + red[1]) * (1.f/512.f);
  float q = 0.f;
  #pragma unroll
  for (int i = 0; i < 4; ++i){ const float d = v[i]-mean; q += d*d; }
  #pragma unroll
  for (int off = 1; off < 64; off <<= 1) q += __shfl_xor(q, off);
  if ((t & 63) == 0) red[2 + (t >> 6)] = q;
  __syncthreads();
  const float var = (red[2] + red[3]) * (1.f/512.f);
  const float rs = rsqrtf(var + 1e-5f);
  const float tk = (MODE == 0) ? tkpm[row] : 1.f;
  #pragma unroll
  for (int i = 0; i < 4; ++i){
    const int c = t + i*128;
    const float y = (v[i] - mean) * rs * g[c] + bvec[c];
    outb[(size_t)row*DIM + c] = f2b(y * tk);
  }
}

// ---------------------------------------------------------------- transposes / misc
__global__ __launch_bounds__(256)
void transpose_f2b(const float* __restrict__ in, u16* __restrict__ out, int R, int C)
{
  __shared__ float tile[32][33];
  const int tx = threadIdx.x, ty = threadIdx.y;
  const int r0 = blockIdx.y*32, c0 = blockIdx.x*32;
  #pragma unroll
  for (int i = 0; i < 4; ++i)
    tile[ty + i*8][tx] = in[(size_t)(r0 + ty + i*8)*C + c0 + tx];
  __syncthreads();
  #pragma unroll
  for (int i = 0; i < 4; ++i)
    out[(size_t)(c0 + ty + i*8)*R + r0 + tx] = f2b(tile[tx][ty + i*8]);
}

__global__ __launch_bounds__(256)
void transpose_b2b(const u16* __restrict__ in, u16* __restrict__ out, int R, int C)
{
  __shared__ u16 tile[32][33];
  in  += (size_t)blockIdx.z * R * C;
  out += (size_t)blockIdx.z * R * C;
  const int tx = threadIdx.x, ty = threadIdx.y;
  const int r0 = blockIdx.y*32, c0 = blockIdx.x*32;
  #pragma unroll
  for (int i = 0; i < 4; ++i)
    tile[ty + i*8][tx] = in[(size_t)(r0 + ty + i*8)*C + c0 + tx];
  __syncthreads();
  #pragma unroll
  for (int i = 0; i < 4; ++i)
    out[(size_t)(c0 + ty + i*8)*R + r0 + tx] = tile[tx][ty + i*8];
}

__global__ void cvt_f2b(const float* __restrict__ in, u16* __restrict__ out, int n){
  const int i = blockIdx.x*blockDim.x + threadIdx.x;
  if (i < n) out[i] = f2b(in[i]);
}

__global__ void finalize_k(const float* __restrict__ xres, const float* __restrict__ tkpm,
                           float* __restrict__ out){
  const int i = blockIdx.x*blockDim.x + threadIdx.x;
  out[i] = xres[i] * tkpm[i >> 9];
}

// ---------------------------------------------------------------- launch
extern "C" void kernel_launch(void* const* d_in, const int* in_sizes, int n_in,
                              void* d_out, int out_size, void* d_ws, size_t ws_size,
                              hipStream_t stream)
{
  const float* tgt  = (const float*)d_in[1];
  const float* mem  = (const float*)d_in[2];
  const float* pos  = (const float*)d_in[3];
  const float* tkpm = (const float*)d_in[5];
  const int*   mkpm = (const int*)d_in[6];
  const float* saqw = (const float*)d_in[7];  const float* saqb = (const float*)d_in[8];
  const float* sakw = (const float*)d_in[9];  const float* sakb = (const float*)d_in[10];
  const float* savw = (const float*)d_in[11]; const float* savb = (const float*)d_in[12];
  const float* saow = (const float*)d_in[13]; const float* saob = (const float*)d_in[14];
  const float* caqw = (const float*)d_in[15]; const float* caqb = (const float*)d_in[16];
  const float* cakw = (const float*)d_in[17]; const float* cakb = (const float*)d_in[18];
  const float* cavw = (const float*)d_in[19]; const float* cavb = (const float*)d_in[20];
  const float* caow = (const float*)d_in[21]; const float* caob = (const float*)d_in[22];
  const float* l1w  = (const float*)d_in[23]; const float* l1b  = (const float*)d_in[24];
  const float* l2w  = (const float*)d_in[25]; const float* l2b  = (const float*)d_in[26];
  const float* n1g  = (const float*)d_in[27]; const float* n1b  = (const float*)d_in[28];
  const float* n2g  = (const float*)d_in[29]; const float* n2b  = (const float*)d_in[30];
  const float* n3g  = (const float*)d_in[31]; const float* n3b  = (const float*)d_in[32];

  if (ws_size < 58720256) return;  // need ~56 MB of scratch

  char* ws = (char*)d_ws;
  float* xres = (float*)(ws + 0);          // 4096x512 f32   (8 MB)
  u16* t2n    = (u16*)(ws + 8388608);      // 4096x512 bf16  (4 MB)
  u16* qb     = (u16*)(ws + 12582912);
  u16* kb     = (u16*)(ws + 16777216);
  u16* vb     = (u16*)(ws + 20971520);
  u16* vt     = (u16*)(ws + 25165824);     // [B][512][2048] bf16
  u16* attno  = (u16*)(ws + 29360128);
  u16* memb   = (u16*)(ws + 33554432);
  u16* ffh    = (u16*)(ws + 37748736);     // 4096x2048 bf16 (16 MB)
  u16* wt     = (u16*)(ws + 54525952);     // transposed weight scratch (2 MB)

  float* out = (float*)d_out;

  #define TW(W, R, C) transpose_f2b<<<dim3((C)/32, (R)/32), dim3(32,8), 0, stream>>>(W, wt, R, C)

  cvt_f2b<<<dim3(MROWS*DIM/256), 256, 0, stream>>>(mem, memb, MROWS*DIM);
  ln_kernel<0><<<MROWS, 128, 0, stream>>>(tgt, pos, tkpm, n1g, n1b, xres, t2n);

  // ---- self attention
  TW(saqw, 512, 512);
  gemm_bt<EPI_SCALEQ><<<dim3(4,32), 256, 0, stream>>>(t2n, wt, saqb, qb, nullptr, 512, 512);
  TW(sakw, 512, 512);
  gemm_bt<EPI_BIAS><<<dim3(4,32), 256, 0, stream>>>(t2n, wt, sakb, kb, nullptr, 512, 512);
  TW(savw, 512, 512);
  gemm_bt<EPI_BIAS><<<dim3(4,32), 256, 0, stream>>>(t2n, wt, savb, vb, nullptr, 512, 512);
  transpose_b2b<<<dim3(512/32, 2048/32, NB), dim3(32,8), 0, stream>>>(vb, vt, 2048, 512);
  attn_kernel<true><<<dim3(QL/16, NH, NB), 64, 0, stream>>>(qb, kb, vt, nullptr, attno);
  TW(saow, 512, 512);
  gemm_bt<EPI_RES><<<dim3(4,32), 256, 0, stream>>>(attno, wt, saob, nullptr, xres, 512, 512);

  ln_kernel<1><<<MROWS, 128, 0, stream>>>(xres, nullptr, nullptr, n2g, n2b, nullptr, t2n);

  // ---- cross attention
  TW(caqw, 512, 512);
  gemm_bt<EPI_SCALEQ><<<dim3(4,32), 256, 0, stream>>>(t2n, wt, caqb, qb, nullptr, 512, 512);
  TW(cakw, 512, 512);
  gemm_bt<EPI_BIAS><<<dim3(4,32), 256, 0, stream>>>(memb, wt, cakb, kb, nullptr, 512, 512);
  TW(cavw, 512, 512);
  gemm_bt<EPI_BIAS><<<dim3(4,32), 256, 0, stream>>>(memb, wt, cavb, vb, nullptr, 512, 512);
  transpose_b2b<<<dim3(512/32, 2048/32, NB), dim3(32,8), 0, stream>>>(vb, vt, 2048, 512);
  attn_kernel<false><<<dim3(QL/16, NH, NB), 64, 0, stream>>>(qb, kb, vt, mkpm, attno);
  TW(caow, 512, 512);
  gemm_bt<EPI_RES><<<dim3(4,32), 256, 0, stream>>>(attno, wt, caob, nullptr, xres, 512, 512);

  ln_kernel<1><<<MROWS, 128, 0, stream>>>(xres, nullptr, nullptr, n3g, n3b, nullptr, t2n);

  // ---- feed-forward
  TW(l1w, 512, 2048);
  gemm_bt<EPI_RELU><<<dim3(16,32), 256, 0, stream>>>(t2n, wt, l1b, ffh, nullptr, 512, 2048);
  TW(l2w, 2048, 512);
  gemm_bt<EPI_RES><<<dim3(4,32), 256, 0, stream>>>(ffh, wt, l2b, nullptr, xres, 2048, 512);

  finalize_k<<<dim3(MROWS*DIM/256), 256, 0, stream>>>(xres, tkpm, out);

  #undef TW
}

// Round 2
// 541.533 us; speedup vs baseline: 1.0096x; 1.0096x over previous
//
#include <hip/hip_runtime.h>
#include <hip/hip_bf16.h>
#include <stdint.h>

#define QL   2048
#define KLn  2048
#define DIM  512
#define NH   8
#define DH   64
#define NB   2
#define MROWS (NB*QL)   // 4096
#define FFD  2048

typedef unsigned short u16;
typedef unsigned int u32;
typedef __attribute__((ext_vector_type(8))) short short8;
typedef __attribute__((ext_vector_type(4))) float f32x4;

__device__ __forceinline__ u16 f2b(float f){
  union { float f; u32 i; } v; v.f = f;
  u32 r = v.i + 0x7FFFu + ((v.i >> 16) & 1u);
  return (u16)(r >> 16);
}
// pack two fp32 -> bf16x2 word (round-half-up; inputs are softmax probs >= 0)
__device__ __forceinline__ u32 pack2(float a, float b){
  union { float f; u32 i; } va, vb; va.f = a; vb.f = b;
  return ((va.i + 0x8000u) >> 16) | ((vb.i + 0x8000u) & 0xFFFF0000u);
}

typedef __attribute__((address_space(3))) void as3void;
typedef __attribute__((address_space(1))) void as1void;
__device__ __forceinline__ void gload_lds16(const void* g, void* l){
  __builtin_amdgcn_global_load_lds((as1void*)g, (as3void*)l, 16, 0, 0);
}

// ---------------------------------------------------------------- GEMM
// C[M,N] = A[M,K](bf16) * Bt[N,K]^T(bf16) + bias
#define BM 128
#define BN 128
#define BK 32
enum { EPI_BIAS=0, EPI_SCALEQ=1, EPI_RELU=2, EPI_RES=3 };
// 1/sqrt(64) * log2(e): folds softmax exp->exp2 conversion into Q scale
#define QSCALE 0.1803368801111244f

template<int EPI>
__global__ __launch_bounds__(256, 2)
void gemm_bt(const u16* __restrict__ A, const u16* __restrict__ Bt,
             const float* __restrict__ bias,
             u16* __restrict__ Obf, float* __restrict__ Ores,
             int K, int N)
{
  __shared__ __align__(16) u16 As[BM*BK];
  __shared__ __align__(16) u16 Bs[BN*BK];
  const int t  = threadIdx.x;
  const int l  = t & 63;
  const int lq = l & 15, lg = l >> 4;
  const int w  = t >> 6;
  const int wm = (w >> 1) * 64;
  const int wn = (w & 1) * 64;
  const int m0 = blockIdx.y * BM;
  const int n0 = blockIdx.x * BN;

  const int srow  = t >> 2;        // 0..63
  const int skseg = (t & 3) * 8;   // 0,8,16,24

  const u16* Ag = A  + (size_t)(m0 + srow) * K + skseg;
  const u16* Bg = Bt + (size_t)(n0 + srow) * K + skseg;
  u16* As0 = &As[srow*BK + skseg];
  u16* As1 = &As[(srow+64)*BK + skseg];
  u16* Bs0 = &Bs[srow*BK + skseg];
  u16* Bs1 = &Bs[(srow+64)*BK + skseg];
  const size_t rowhop = (size_t)64 * K;

  f32x4 acc[4][4];
  #pragma unroll
  for (int i=0;i<4;i++)
    #pragma unroll
    for (int j=0;j<4;j++) acc[i][j] = (f32x4){0.f,0.f,0.f,0.f};

  for (int k0 = 0; k0 < K; k0 += BK){
    gload_lds16(Ag + k0,          As0);
    gload_lds16(Ag + k0 + rowhop, As1);
    gload_lds16(Bg + k0,          Bs0);
    gload_lds16(Bg + k0 + rowhop, Bs1);
    __syncthreads();
    short8 af[4], bf[4];
    #pragma unroll
    for (int i=0;i<4;i++) af[i] = *(const short8*)&As[(wm + i*16 + lq)*BK + lg*8];
    #pragma unroll
    for (int j=0;j<4;j++) bf[j] = *(const short8*)&Bs[(wn + j*16 + lq)*BK + lg*8];
    #pragma unroll
    for (int i=0;i<4;i++)
      #pragma unroll
      for (int j=0;j<4;j++)
        acc[i][j] = __builtin_amdgcn_mfma_f32_16x16x32_bf16(af[i], bf[j], acc[i][j], 0,0,0);
    __syncthreads();
  }

  #pragma unroll
  for (int i=0;i<4;i++){
    #pragma unroll
    for (int j=0;j<4;j++){
      #pragma unroll
      for (int r=0;r<4;r++){
        const int row = m0 + wm + i*16 + lg*4 + r;
        const int col = n0 + wn + j*16 + lq;
        float v = acc[i][j][r] + bias[col];
        if (EPI == EPI_SCALEQ) v *= QSCALE;
        if (EPI == EPI_RELU)   v = fmaxf(v, 0.f);
        if (EPI == EPI_RES)    Ores[(size_t)row*N + col] += v;
        else                   Obf[(size_t)row*N + col] = f2b(v);
      }
    }
  }
}

// ---------------------------------------------------------------- attention v2
// Swapped QK^T (S^T = K x Q^T) so each lane owns one q-row's scores in-register.
// KVBLK=64. P->PV uses a permuted MFMA K-slot mapping so the P fragment is
// exactly the lane-local registers (zero cross-lane traffic); V is stored
// pre-permuted to match. exp2-domain softmax (log2e folded into Q scale).
template<bool CAUSAL>
__global__ __launch_bounds__(64)
void attn2(const u16* __restrict__ Q, const u16* __restrict__ Kb,
           const u16* __restrict__ Vt, const float* __restrict__ bias,
           u16* __restrict__ O)
{
  const int l  = threadIdx.x;
  const int lq = l & 15, lg = l >> 4;
  const int q0 = blockIdx.x * 16;
  const int h  = blockIdx.y;
  const int b  = blockIdx.z;

  short8 aq[2];
  #pragma unroll
  for (int kc = 0; kc < 2; ++kc)
    aq[kc] = *(const short8*)(Q + (size_t)(b*QL + q0 + lq)*DIM + h*DH + kc*32 + lg*8);

  f32x4 ctx[4];
  #pragma unroll
  for (int d = 0; d < 4; ++d) ctx[d] = (f32x4){0.f,0.f,0.f,0.f};
  float m = -INFINITY, lsum = 0.f;

  const int ntiles = CAUSAL ? ((q0 + 16 + 63) >> 6) : (KLn >> 6);
  for (int t = 0; t < ntiles; ++t){
    const int kvs = t * 64;
    f32x4 s[4];
    #pragma unroll
    for (int sub = 0; sub < 4; ++sub) s[sub] = (f32x4){0.f,0.f,0.f,0.f};
    #pragma unroll
    for (int sub = 0; sub < 4; ++sub){
      const u16* kp = Kb + (size_t)(b*KLn + kvs + sub*16 + lq)*DIM + h*DH;
      #pragma unroll
      for (int kc = 0; kc < 2; ++kc){
        short8 bk = *(const short8*)(kp + kc*32 + lg*8);
        s[sub] = __builtin_amdgcn_mfma_f32_16x16x32_bf16(bk, aq[kc], s[sub], 0,0,0);
      }
    }
    // masking.  lane holds S[kv = kvs+sub*16+lg*4+r][q = q0+lq]
    if (CAUSAL){
      if (kvs + 63 > q0){
        #pragma unroll
        for (int sub = 0; sub < 4; ++sub)
          #pragma unroll
          for (int r = 0; r < 4; ++r)
            if (kvs + sub*16 + lg*4 + r > q0 + lq) s[sub][r] = -INFINITY;
      }
    } else {
      #pragma unroll
      for (int sub = 0; sub < 4; ++sub){
        f32x4 bv = *(const f32x4*)(bias + b*KLn + kvs + sub*16 + lg*4);
        s[sub] += bv;
      }
    }
    // online softmax: all 16 scores for q = q0+lq are in-lane
    float pmax = s[0][0];
    #pragma unroll
    for (int sub = 0; sub < 4; ++sub)
      #pragma unroll
      for (int r = 0; r < 4; ++r) pmax = fmaxf(pmax, s[sub][r]);
    pmax = fmaxf(pmax, __shfl_xor(pmax, 16));
    pmax = fmaxf(pmax, __shfl_xor(pmax, 32));
    const float mnew = fmaxf(m, pmax);
    const float corr = exp2f(m - mnew);
    float psum = 0.f;
    u32 pk[4][2];
    #pragma unroll
    for (int sub = 0; sub < 4; ++sub){
      float p0 = exp2f(s[sub][0] - mnew);
      float p1 = exp2f(s[sub][1] - mnew);
      float p2 = exp2f(s[sub][2] - mnew);
      float p3 = exp2f(s[sub][3] - mnew);
      psum += (p0 + p1) + (p2 + p3);
      pk[sub][0] = pack2(p0, p1);
      pk[sub][1] = pack2(p2, p3);
    }
    psum += __shfl_xor(psum, 16);
    psum += __shfl_xor(psum, 32);
    lsum = lsum * corr + psum;
    m = mnew;
    // redistribute corr to ctx rows (ctx row q-local = lg*4+r, state lives at lane q)
    float corr4[4];
    #pragma unroll
    for (int r = 0; r < 4; ++r) corr4[r] = __shfl(corr, lg*4 + r);
    #pragma unroll
    for (int d = 0; d < 4; ++d)
      #pragma unroll
      for (int r = 0; r < 4; ++r) ctx[d][r] *= corr4[r];
    // PV: A-fragment = lane-local P registers under the permuted K-slot map
    union { u32 u[4]; short8 s8; } pa0, pa1;
    pa0.u[0] = pk[0][0]; pa0.u[1] = pk[0][1]; pa0.u[2] = pk[1][0]; pa0.u[3] = pk[1][1];
    pa1.u[0] = pk[2][0]; pa1.u[1] = pk[2][1]; pa1.u[2] = pk[3][0]; pa1.u[3] = pk[3][1];
    #pragma unroll
    for (int d0 = 0; d0 < 4; ++d0){
      const u16* vp = Vt + (size_t)(b*DIM + h*DH + d0*16 + lq)*KLn + kvs;
      short8 v0 = *(const short8*)(vp + lg*8);
      short8 v1 = *(const short8*)(vp + 32 + lg*8);
      ctx[d0] = __builtin_amdgcn_mfma_f32_16x16x32_bf16(pa0.s8, v0, ctx[d0], 0,0,0);
      ctx[d0] = __builtin_amdgcn_mfma_f32_16x16x32_bf16(pa1.s8, v1, ctx[d0], 0,0,0);
    }
  }
  float inv4[4];
  #pragma unroll
  for (int r = 0; r < 4; ++r) inv4[r] = 1.f / __shfl(lsum, lg*4 + r);
  #pragma unroll
  for (int d0 = 0; d0 < 4; ++d0)
    #pragma unroll
    for (int r = 0; r < 4; ++r)
      O[(size_t)(b*QL + q0 + lg*4 + r)*DIM + h*DH + d0*16 + lq] = f2b(ctx[d0][r] * inv4[r]);
}

// ---------------------------------------------------------------- layernorm
template<int MODE>
__global__ __launch_bounds__(128)
void ln_kernel(const float* __restrict__ in0, const float* __restrict__ in1,
               const float* __restrict__ tkpm,
               const float* __restrict__ g, const float* __restrict__ bvec,
               float* __restrict__ xres, u16* __restrict__ outb)
{
  const int row = blockIdx.x;
  const int t = threadIdx.x;
  float v[4];
  #pragma unroll
  for (int i = 0; i < 4; ++i){
    const int c = t + i*128;
    float x = in0[(size_t)row*DIM + c];
    if (MODE == 0){
      x += in1[(size_t)row*DIM + c];
      xres[(size_t)row*DIM + c] = x;
    }
    v[i] = x;
  }
  float s = v[0]+v[1]+v[2]+v[3];
  #pragma unroll
  for (int off = 1; off < 64; off <<= 1) s += __shfl_xor(s, off);
  __shared__ float red[4];
  if ((t & 63) == 0) red[t >> 6] = s;
  __syncthreads();
  const float mean = (red[0] + red[1]) * (1.f/512.f);
  float q = 0.f;
  #pragma unroll
  for (int i = 0; i < 4; ++i){ const float d = v[i]-mean; q += d*d; }
  #pragma unroll
  for (int off = 1; off < 64; off <<= 1) q += __shfl_xor(q, off);
  if ((t & 63) == 0) red[2 + (t >> 6)] = q;
  __syncthreads();
  const float var = (red[2] + red[3]) * (1.f/512.f);
  const float rs = rsqrtf(var + 1e-5f);
  const float tk = (MODE == 0) ? tkpm[row] : 1.f;
  #pragma unroll
  for (int i = 0; i < 4; ++i){
    const int c = t + i*128;
    const float y = (v[i] - mean) * rs * g[c] + bvec[c];
    outb[(size_t)row*DIM + c] = f2b(y * tk);
  }
}

// ---------------------------------------------------------------- transposes / misc
__global__ __launch_bounds__(256)
void transpose_f2b(const float* __restrict__ in, u16* __restrict__ out, int R, int C)
{
  __shared__ float tile[32][33];
  const int tx = threadIdx.x, ty = threadIdx.y;
  const int r0 = blockIdx.y*32, c0 = blockIdx.x*32;
  #pragma unroll
  for (int i = 0; i < 4; ++i)
    tile[ty + i*8][tx] = in[(size_t)(r0 + ty + i*8)*C + c0 + tx];
  __syncthreads();
  #pragma unroll
  for (int i = 0; i < 4; ++i)
    out[(size_t)(c0 + ty + i*8)*R + r0 + tx] = f2b(tile[tx][ty + i*8]);
}

// all eight 512x512 attention weights in one launch (blockIdx.z selects)
__global__ __launch_bounds__(256)
void transpose8_f2b(const float* w0, const float* w1, const float* w2, const float* w3,
                    const float* w4, const float* w5, const float* w6, const float* w7,
                    u16* __restrict__ out)
{
  __shared__ float tile[32][33];
  const float* wp[8] = {w0,w1,w2,w3,w4,w5,w6,w7};
  const float* w = wp[blockIdx.z];
  u16* o = out + (size_t)blockIdx.z * 512 * 512;
  const int tx = threadIdx.x, ty = threadIdx.y;
  const int r0 = blockIdx.y*32, c0 = blockIdx.x*32;
  #pragma unroll
  for (int i = 0; i < 4; ++i)
    tile[ty + i*8][tx] = w[(size_t)(r0 + ty + i*8)*512 + c0 + tx];
  __syncthreads();
  #pragma unroll
  for (int i = 0; i < 4; ++i)
    o[(size_t)(c0 + ty + i*8)*512 + r0 + tx] = f2b(tile[tx][ty + i*8]);
}

// V [b][kv][512] -> Vt [b][d][slot(kv)] with the PV K-slot permutation folded in:
// within each 32-kv group, slot = ((kv>>2)&3)<<3 | ((kv>>4)&1)<<2 | (kv&3)
__global__ __launch_bounds__(256)
void transpose_vperm(const u16* __restrict__ in, u16* __restrict__ out)
{
  __shared__ u16 tile[32][33];
  in  += (size_t)blockIdx.z * KLn * DIM;
  out += (size_t)blockIdx.z * KLn * DIM;
  const int tx = threadIdx.x, ty = threadIdx.y;
  const int r0 = blockIdx.y*32, c0 = blockIdx.x*32;   // r=kv, c=d
  #pragma unroll
  for (int i = 0; i < 4; ++i)
    tile[ty + i*8][tx] = in[(size_t)(r0 + ty + i*8)*DIM + c0 + tx];
  __syncthreads();
  const int kv = r0 + tx;
  const int slot = (kv & ~31) | (((kv>>2)&3)<<3) | (((kv>>4)&1)<<2) | (kv&3);
  #pragma unroll
  for (int i = 0; i < 4; ++i)
    out[(size_t)(c0 + ty + i*8)*KLn + slot] = tile[tx][ty + i*8];
}

__global__ void cvt_f2b(const float* __restrict__ in, u16* __restrict__ out, int n){
  const int i = blockIdx.x*blockDim.x + threadIdx.x;
  if (i < n) out[i] = f2b(in[i]);
}

__global__ void maskbias_k(const int* __restrict__ mkpm, float* __restrict__ bias, int n){
  const int i = blockIdx.x*blockDim.x + threadIdx.x;
  if (i < n) bias[i] = mkpm[i] ? 0.f : -1e30f;
}

__global__ void finalize_k(const float* __restrict__ xres, const float* __restrict__ tkpm,
                           float* __restrict__ out){
  const int i = blockIdx.x*blockDim.x + threadIdx.x;
  out[i] = xres[i] * tkpm[i >> 9];
}

// ---------------------------------------------------------------- launch
extern "C" void kernel_launch(void* const* d_in, const int* in_sizes, int n_in,
                              void* d_out, int out_size, void* d_ws, size_t ws_size,
                              hipStream_t stream)
{
  const float* tgt  = (const float*)d_in[1];
  const float* mem  = (const float*)d_in[2];
  const float* pos  = (const float*)d_in[3];
  const float* tkpm = (const float*)d_in[5];
  const int*   mkpm = (const int*)d_in[6];
  const float* saqw = (const float*)d_in[7];  const float* saqb = (const float*)d_in[8];
  const float* sakw = (const float*)d_in[9];  const float* sakb = (const float*)d_in[10];
  const float* savw = (const float*)d_in[11]; const float* savb = (const float*)d_in[12];
  const float* saow = (const float*)d_in[13]; const float* saob = (const float*)d_in[14];
  const float* caqw = (const float*)d_in[15]; const float* caqb = (const float*)d_in[16];
  const float* cakw = (const float*)d_in[17]; const float* cakb = (const float*)d_in[18];
  const float* cavw = (const float*)d_in[19]; const float* cavb = (const float*)d_in[20];
  const float* caow = (const float*)d_in[21]; const float* caob = (const float*)d_in[22];
  const float* l1w  = (const float*)d_in[23]; const float* l1b  = (const float*)d_in[24];
  const float* l2w  = (const float*)d_in[25]; const float* l2b  = (const float*)d_in[26];
  const float* n1g  = (const float*)d_in[27]; const float* n1b  = (const float*)d_in[28];
  const float* n2g  = (const float*)d_in[29]; const float* n2b  = (const float*)d_in[30];
  const float* n3g  = (const float*)d_in[31]; const float* n3b  = (const float*)d_in[32];

  if (ws_size < 58720256) return;  // 56 MB scratch

  char* ws = (char*)d_ws;
  float* xres = (float*)(ws);                      // 8 MB  f32 residual
  u16* t2n    = (u16*)(ws + (8u<<20));             // 4 MB  LN out / attn out (aliased, stream-ordered)
  u16* qb     = (u16*)(ws + (12u<<20));            // 4 MB
  u16* kb     = (u16*)(ws + (16u<<20));            // 4 MB
  u16* vb     = (u16*)(ws + (20u<<20));            // 4 MB  (later reused for FF weightT)
  u16* vt     = (u16*)(ws + (24u<<20));            // 4 MB  permuted V^T
  float* bias = (float*)(ws + (28u<<20));          // 16 KB cross-attn additive mask
  u16* memb   = (u16*)(ws + (32u<<20));            // 4 MB  memory in bf16
  u16* ffh    = (u16*)(ws + (36u<<20));            // 16 MB FF hidden
  u16* wtA    = (u16*)(ws + (52u<<20));            // 4 MB  8x 512x512 attn weightT
  u16* l1wt   = vb;                                // 2 MB  (after cross vperm)
  u16* l2wt   = (u16*)(ws + (22u<<20));            // 2 MB

  float* out = (float*)d_out;
  const int W55 = 512*512;

  maskbias_k<<<dim3(NB*KLn/256), 256, 0, stream>>>(mkpm, bias, NB*KLn);
  cvt_f2b<<<dim3(MROWS*DIM/256), 256, 0, stream>>>(mem, memb, MROWS*DIM);
  ln_kernel<0><<<MROWS, 128, 0, stream>>>(tgt, pos, tkpm, n1g, n1b, xres, t2n);
  transpose8_f2b<<<dim3(16,16,8), dim3(32,8), 0, stream>>>(saqw, sakw, savw, saow,
                                                           caqw, cakw, cavw, caow, wtA);

  // ---- self attention
  gemm_bt<EPI_SCALEQ><<<dim3(4,32), 256, 0, stream>>>(t2n, wtA + 0*W55, saqb, qb, nullptr, 512, 512);
  gemm_bt<EPI_BIAS>  <<<dim3(4,32), 256, 0, stream>>>(t2n, wtA + 1*W55, sakb, kb, nullptr, 512, 512);
  gemm_bt<EPI_BIAS>  <<<dim3(4,32), 256, 0, stream>>>(t2n, wtA + 2*W55, savb, vb, nullptr, 512, 512);
  transpose_vperm<<<dim3(DIM/32, KLn/32, NB), dim3(32,8), 0, stream>>>(vb, vt);
  attn2<true><<<dim3(QL/16, NH, NB), 64, 0, stream>>>(qb, kb, vt, nullptr, t2n);
  gemm_bt<EPI_RES>   <<<dim3(4,32), 256, 0, stream>>>(t2n, wtA + 3*W55, saob, nullptr, xres, 512, 512);

  ln_kernel<1><<<MROWS, 128, 0, stream>>>(xres, nullptr, nullptr, n2g, n2b, nullptr, t2n);

  // ---- cross attention
  gemm_bt<EPI_SCALEQ><<<dim3(4,32), 256, 0, stream>>>(t2n,  wtA + 4*W55, caqb, qb, nullptr, 512, 512);
  gemm_bt<EPI_BIAS>  <<<dim3(4,32), 256, 0, stream>>>(memb, wtA + 5*W55, cakb, kb, nullptr, 512, 512);
  gemm_bt<EPI_BIAS>  <<<dim3(4,32), 256, 0, stream>>>(memb, wtA + 6*W55, cavb, vb, nullptr, 512, 512);
  transpose_vperm<<<dim3(DIM/32, KLn/32, NB), dim3(32,8), 0, stream>>>(vb, vt);
  transpose_f2b<<<dim3(FFD/32, 512/32), dim3(32,8), 0, stream>>>(l1w, l1wt, 512, FFD);
  transpose_f2b<<<dim3(512/32, FFD/32), dim3(32,8), 0, stream>>>(l2w, l2wt, FFD, 512);
  attn2<false><<<dim3(QL/16, NH, NB), 64, 0, stream>>>(qb, kb, vt, bias, t2n);
  gemm_bt<EPI_RES>   <<<dim3(4,32), 256, 0, stream>>>(t2n, wtA + 7*W55, caob, nullptr, xres, 512, 512);

  ln_kernel<1><<<MROWS, 128, 0, stream>>>(xres, nullptr, nullptr, n3g, n3b, nullptr, t2n);

  // ---- feed-forward
  gemm_bt<EPI_RELU><<<dim3(16,32), 256, 0, stream>>>(t2n, l1wt, l1b, ffh, nullptr, 512, FFD);
  gemm_bt<EPI_RES> <<<dim3(4,32),  256, 0, stream>>>(ffh, l2wt, l2b, nullptr, xres, FFD, 512);

  finalize_k<<<dim3(MROWS*DIM/256), 256, 0, stream>>>(xres, tkpm, out);
}